// Round 9
// baseline (112.446 us; speedup 1.0000x reference)
//
#include <hip/hip_runtime.h>

constexpr int PIX   = 513 * 513;      // 263169 = 2056*128 + 1
constexpr int NTILE = 128;
constexpr int NFULL = PIX / NTILE;    // 2056 full tiles; 1 tail pixel
constexpr int GRID  = 512;            // 2 blocks/CU, persistent-ish

typedef short bf16x8 __attribute__((ext_vector_type(8)));
typedef float f32x4  __attribute__((ext_vector_type(4)));

// RNE f32 -> bf16 bits
__device__ __forceinline__ unsigned short f2bf(float f) {
    unsigned u = __builtin_bit_cast(unsigned, f);
    u += 0x7fffu + ((u >> 16) & 1u);
    return (unsigned short)(u >> 16);
}
__device__ __forceinline__ unsigned pack2(float a, float b) {
    return (unsigned)f2bf(a) | ((unsigned)f2bf(b) << 16);
}

// C[128 x P] = Wbig[128 x 128] * X[128 x P] + bias
//   X rows 0..63 = inputs_over, 64..127 = inputs_under
//   Wbig = [[w+, w-], [w-, w+]]; C rows 0..63 -> out_over, 64..127 -> out_under
__global__ __launch_bounds__(512, 4) void mfma_bounds_kernel(
    const float* __restrict__ under,
    const float* __restrict__ over,
    const float* __restrict__ W,
    const float* __restrict__ bias,
    float* __restrict__ out_under,
    float* __restrict__ out_over)
{
    __shared__ alignas(16) unsigned short Xt[2][NTILE * 128];  // 2 x 32 KB, swizzled [px][k]

    const int t    = threadIdx.x;
    const int wv   = t >> 6;        // 8 waves; wave owns C rows [wv*16, wv*16+16)
    const int lane = t & 63;
    const int lrow = lane & 15;
    const int lg   = lane >> 4;
    const int m0   = wv * 16;

    // ---- A fragments from f32 W (16 KB, L2-hot). Built ONCE per block. ----
    bf16x8 A[4];
    {
        const int m = m0 + lrow;
        const float* wr = W + (m & 63) * 64;
        #pragma unroll
        for (int ks = 0; ks < 4; ++ks) {
            const int kbase = ks * 32 + lg * 8;     // 8-aligned, never straddles 64
            const bool same = ((kbase < 64) == (m < 64));
            const float4 wa = *(const float4*)(wr + (kbase & 63));
            const float4 wb = *(const float4*)(wr + (kbase & 63) + 4);
            bf16x8 f;
            f[0] = (short)f2bf(same ? fmaxf(wa.x, 0.f) : fminf(wa.x, 0.f));
            f[1] = (short)f2bf(same ? fmaxf(wa.y, 0.f) : fminf(wa.y, 0.f));
            f[2] = (short)f2bf(same ? fmaxf(wa.z, 0.f) : fminf(wa.z, 0.f));
            f[3] = (short)f2bf(same ? fmaxf(wa.w, 0.f) : fminf(wa.w, 0.f));
            f[4] = (short)f2bf(same ? fmaxf(wb.x, 0.f) : fminf(wb.x, 0.f));
            f[5] = (short)f2bf(same ? fmaxf(wb.y, 0.f) : fminf(wb.y, 0.f));
            f[6] = (short)f2bf(same ? fmaxf(wb.z, 0.f) : fminf(wb.z, 0.f));
            f[7] = (short)f2bf(same ? fmaxf(wb.w, 0.f) : fminf(wb.w, 0.f));
            A[ks] = f;
        }
    }
    float bb[4];
    #pragma unroll
    for (int r = 0; r < 4; ++r)
        bb[r] = bias[(m0 + lg * 4 + r) & 63];

    // ---- staging mapping: thread = (px quad, k octet), float4 loads ----
    const int q   = t & 31;                  // px0 = q*4 .. +3
    const int ro  = t >> 5;                  // 0..15: k rows [ro*8, ro*8+8)
    const float* src = (ro < 8) ? over : under;
    const int rr  = (ro & 7) * 8;            // row within src
    const int k0  = ro * 8;                  // global k
    const int px0 = q * 4;
    const int xwr = (lrow & 7) << 4;

    // ---- prologue: load tile 0 ----
    int tile = blockIdx.x;
    f32x4 ld[8];
    {
        const size_t pb = (size_t)tile * NTILE + px0;
        #pragma unroll
        for (int j = 0; j < 8; ++j)
            ld[j] = *(const f32x4*)(src + (size_t)(rr + j) * PIX + pb);
    }

    int cur = 0;
    while (tile < NFULL) {
        // ---- pack ld -> Xt[cur] (b128 writes, swizzle byte ^= (px&7)<<4) ----
        #pragma unroll
        for (int c = 0; c < 4; ++c) {
            int4 pk;
            pk.x = (int)pack2(ld[0][c], ld[1][c]);
            pk.y = (int)pack2(ld[2][c], ld[3][c]);
            pk.z = (int)pack2(ld[4][c], ld[5][c]);
            pk.w = (int)pack2(ld[6][c], ld[7][c]);
            const int px  = px0 + c;
            const int off = px * 256 + ((k0 * 2) ^ ((px & 7) << 4));
            *(int4*)((char*)&Xt[cur][0] + off) = pk;
        }
        __syncthreads();

        const int pxbase    = tile * NTILE;
        const int tile_next = tile + GRID;

        // ---- issue NEXT tile's loads now; they fly under compute+stores ----
        if (tile_next < NFULL) {
            const size_t pb = (size_t)tile_next * NTILE + px0;
            #pragma unroll
            for (int j = 0; j < 8; ++j)
                ld[j] = *(const f32x4*)(src + (size_t)(rr + j) * PIX + pb);
        }

        // ---- compute from Xt[cur]: two nt-halves of 4 (acc = 16 VGPR) ----
        #pragma unroll
        for (int h = 0; h < 2; ++h) {
            f32x4 acc[4];
            #pragma unroll
            for (int n4 = 0; n4 < 4; ++n4) {
                f32x4 v = {bb[0], bb[1], bb[2], bb[3]};
                acc[n4] = v;
            }
            #pragma unroll
            for (int n4 = 0; n4 < 4; ++n4) {
                const int prow = (h * 4 + n4) * 16 + lrow;
                bf16x8 Bf[4];
                #pragma unroll
                for (int ks = 0; ks < 4; ++ks) {
                    const int ch = ks * 4 + lg;
                    Bf[ks] = *(const bf16x8*)((const char*)&Xt[cur][0] +
                               prow * 256 + ((ch * 16) ^ xwr));
                }
                #pragma unroll
                for (int ks = 0; ks < 4; ++ks)
                    acc[n4] = __builtin_amdgcn_mfma_f32_16x16x32_bf16(
                        A[ks], Bf[ks], acc[n4], 0, 0, 0);
            }
            // store: C[m][p], col = lane&15, row = lg*4 + r (verified layout)
            #pragma unroll
            for (int r = 0; r < 4; ++r) {
                const int m = m0 + lg * 4 + r;
                float* base = (m < 64) ? (out_over  + (size_t)m        * PIX)
                                       : (out_under + (size_t)(m - 64) * PIX);
                #pragma unroll
                for (int n4 = 0; n4 < 4; ++n4)
                    __builtin_nontemporal_store(acc[n4][r],
                        base + pxbase + (h * 4 + n4) * 16 + lrow);
            }
        }

        cur ^= 1;
        tile = tile_next;
    }

    // ---- tail: single leftover pixel (PIX = 2056*128 + 1), last block ----
    if (blockIdx.x == GRID - 1 && t < 128) {
        const int p = NFULL * NTILE;
        const int m = t;
        const int o = m & 63;
        const float* prim = (m < 64) ? over  : under;
        const float* sec  = (m < 64) ? under : over;
        float acc = bias[o];
        for (int i = 0; i < 64; ++i) {
            const float w = W[o * 64 + i];
            acc += fmaxf(w, 0.f) * prim[(size_t)i * PIX + p]
                 + fminf(w, 0.f) * sec [(size_t)i * PIX + p];
        }
        if (m < 64) out_over [(size_t)m        * PIX + p] = acc;
        else        out_under[(size_t)(m - 64) * PIX + p] = acc;
    }
}

extern "C" void kernel_launch(void* const* d_in, const int* in_sizes, int n_in,
                              void* d_out, int out_size, void* d_ws, size_t ws_size,
                              hipStream_t stream) {
    const float* under = (const float*)d_in[0];
    const float* over  = (const float*)d_in[1];
    const float* W     = (const float*)d_in[2];
    const float* bias  = (const float*)d_in[3];
    float* out_under = (float*)d_out;
    float* out_over  = out_under + (size_t)64 * PIX;

    mfma_bounds_kernel<<<GRID, 512, 0, stream>>>(under, over, W, bias,
                                                 out_under, out_over);
}

// Round 10
// 79.570 us; speedup vs baseline: 1.4132x; 1.4132x over previous
//
#include <hip/hip_runtime.h>

constexpr int PIX   = 513 * 513;  // 263169 = 2056*128 + 1
constexpr int NTILE = 128;        // pixels per block

typedef short bf16x8 __attribute__((ext_vector_type(8)));
typedef float f32x4  __attribute__((ext_vector_type(4)));

// Precomputed Wbig = [[w+, w-], [w-, w+]] as bf16 bits, natural [m][k] layout.
__device__ unsigned short g_Wbig[128 * 128];  // 32 KB, L2-hot

// RNE f32 -> bf16 bits
__device__ __forceinline__ unsigned short f2bf(float f) {
    unsigned u = __builtin_bit_cast(unsigned, f);
    u += 0x7fffu + ((u >> 16) & 1u);
    return (unsigned short)(u >> 16);
}
__device__ __forceinline__ unsigned pack2(float a, float b) {
    return (unsigned)f2bf(a) | ((unsigned)f2bf(b) << 16);
}

__global__ __launch_bounds__(256) void prep_kernel(const float* __restrict__ W) {
    const int idx = blockIdx.x * 256 + threadIdx.x;   // 64 blocks -> 16384
    const int m = idx >> 7, k = idx & 127;
    const float w = W[(m & 63) * 64 + (k & 63)];
    const bool same = ((m < 64) == (k < 64));
    g_Wbig[idx] = f2bf(same ? fmaxf(w, 0.f) : fminf(w, 0.f));
}

// C[128 x P] = Wbig[128 x 128] * X[128 x P] + bias
//   X rows 0..63 = inputs_over, rows 64..127 = inputs_under
//   C rows 0..63 -> out_over, 64..127 -> out_under
__global__ __launch_bounds__(256, 2) void mfma_bounds_kernel(
    const float* __restrict__ under,
    const float* __restrict__ over,
    const float* __restrict__ W,
    const float* __restrict__ bias,
    float* __restrict__ out_under,
    float* __restrict__ out_over)
{
    __shared__ alignas(16) unsigned short Xt[NTILE * 128];  // bf16 [px][k], 32 KB, swizzled

    const int t = threadIdx.x;
    const int pxbase = blockIdx.x * NTILE;

    if (pxbase + NTILE > PIX) {
        // ---- tail block (1 pixel): scalar f32 path ----
        if (t < 128) {
            const int m = t;
            const int o = m & 63;
            const float* prim = (m < 64) ? over  : under;
            const float* sec  = (m < 64) ? under : over;
            for (int p = pxbase; p < PIX; ++p) {
                float acc = bias[o];
                for (int i = 0; i < 64; ++i) {
                    const float w = W[o * 64 + i];
                    acc += fmaxf(w, 0.f) * prim[(size_t)i * PIX + p]
                         + fminf(w, 0.f) * sec [(size_t)i * PIX + p];
                }
                if (m < 64) out_over [(size_t)m        * PIX + p] = acc;
                else        out_under[(size_t)(m - 64) * PIX + p] = acc;
            }
        }
        return;
    }

    // ---- stage X tile: 16 float4 loads + 8 swizzled ds_write_b128 per thread ----
    // thread = (px quad, k 16-row group): q = t&31 -> px0 = 4q; ro = t>>5 (0..7)
    {
        const int q   = t & 31;
        const int ro  = t >> 5;                    // 0..7
        const float* src = (ro < 4) ? over : under;
        const int rr  = (ro & 3) * 16;             // row within src
        const int px0 = q * 4;
        const size_t pb = (size_t)pxbase + px0;

        f32x4 ld[16];
        #pragma unroll
        for (int j = 0; j < 16; ++j)
            ld[j] = *(const f32x4*)(src + (size_t)(rr + j) * PIX + pb);

        #pragma unroll
        for (int c = 0; c < 4; ++c) {
            const int px = px0 + c;
            const int xw = (px & 7) << 4;
            #pragma unroll
            for (int oct = 0; oct < 2; ++oct) {    // k octets within the 16 rows
                int4 pk;
                pk.x = (int)pack2(ld[oct * 8 + 0][c], ld[oct * 8 + 1][c]);
                pk.y = (int)pack2(ld[oct * 8 + 2][c], ld[oct * 8 + 3][c]);
                pk.z = (int)pack2(ld[oct * 8 + 4][c], ld[oct * 8 + 5][c]);
                pk.w = (int)pack2(ld[oct * 8 + 6][c], ld[oct * 8 + 7][c]);
                const int kbyte = ro * 32 + oct * 16;   // = k0 * 2
                const int off = px * 256 + (kbyte ^ xw);
                *(int4*)((char*)Xt + off) = pk;
            }
        }
    }

    // ---- A fragments from bf16 g_Wbig (8 aligned 16B loads, L2-hot) ----
    const int wv   = t >> 6;       // 4 waves; wave owns C rows [wv*32, wv*32+32)
    const int lane = t & 63;
    const int lrow = lane & 15;
    const int lg   = lane >> 4;
    const int m0   = wv * 32;

    bf16x8 A[2][4];
    #pragma unroll
    for (int mt = 0; mt < 2; ++mt)
        #pragma unroll
        for (int ks = 0; ks < 4; ++ks)
            A[mt][ks] = *(const bf16x8*)&g_Wbig[(m0 + mt * 16 + lrow) * 128 +
                                                ks * 32 + lg * 8];

    float bb[2][4];
    #pragma unroll
    for (int mt = 0; mt < 2; ++mt)
        #pragma unroll
        for (int r = 0; r < 4; ++r)
            bb[mt][r] = bias[(m0 + mt * 16 + lg * 4 + r) & 63];

    __syncthreads();

    // prow = nt*16 + lrow  =>  (prow & 7) == (lrow & 7)
    const int xwr = (lrow & 7) << 4;

    // ---- compute: R6-verbatim shape (acc[2][8], single pass) ----
    f32x4 acc[2][8];
    #pragma unroll
    for (int mt = 0; mt < 2; ++mt)
        #pragma unroll
        for (int nt = 0; nt < 8; ++nt) {
            f32x4 v = {bb[mt][0], bb[mt][1], bb[mt][2], bb[mt][3]};
            acc[mt][nt] = v;
        }

    #pragma unroll
    for (int nt = 0; nt < 8; ++nt) {
        const int prow = nt * 16 + lrow;
        bf16x8 Bf[4];
        #pragma unroll
        for (int ks = 0; ks < 4; ++ks) {
            const int ch = ks * 4 + lg;
            Bf[ks] = *(const bf16x8*)((const char*)Xt + prow * 256 + ((ch * 16) ^ xwr));
        }
        #pragma unroll
        for (int mt = 0; mt < 2; ++mt)
            #pragma unroll
            for (int ks = 0; ks < 4; ++ks)
                acc[mt][nt] = __builtin_amdgcn_mfma_f32_16x16x32_bf16(
                    A[mt][ks], Bf[ks], acc[mt][nt], 0, 0, 0);
    }

    // ---- store: C[m][p], col = lane&15, row = lg*4 + r (verified layout) ----
    #pragma unroll
    for (int mt = 0; mt < 2; ++mt)
        #pragma unroll
        for (int r = 0; r < 4; ++r) {
            const int m = m0 + mt * 16 + lg * 4 + r;
            float* base = (m < 64) ? (out_over  + (size_t)m        * PIX)
                                   : (out_under + (size_t)(m - 64) * PIX);
            #pragma unroll
            for (int nt = 0; nt < 8; ++nt)
                __builtin_nontemporal_store(acc[mt][nt][r],
                    base + pxbase + nt * 16 + lrow);
        }
}

extern "C" void kernel_launch(void* const* d_in, const int* in_sizes, int n_in,
                              void* d_out, int out_size, void* d_ws, size_t ws_size,
                              hipStream_t stream) {
    const float* under = (const float*)d_in[0];
    const float* over  = (const float*)d_in[1];
    const float* W     = (const float*)d_in[2];
    const float* bias  = (const float*)d_in[3];
    float* out_under = (float*)d_out;
    float* out_over  = out_under + (size_t)64 * PIX;

    prep_kernel<<<64, 256, 0, stream>>>(W);

    const int blocks = (PIX + NTILE - 1) / NTILE;  // 2057
    mfma_bounds_kernel<<<blocks, 256, 0, stream>>>(under, over, W, bias,
                                                   out_under, out_over);
}